// Round 11
// baseline (98.353 us; speedup 1.0000x reference)
//
#include <hip/hip_runtime.h>
#include <hip/hip_bf16.h>
#include <cstdint>
#include <cstddef>

#define M_DIM 4096
#define N_DIM 4096
#define K_DIM 4096
#define KBLKS (K_DIM / 64)    // 64 granule-columns of K=64
#define NT    (K_DIM / 128)   // 32 K-tiles of BK=128

using i32x4   = __attribute__((ext_vector_type(4))) int;
using s8x16   = __attribute__((ext_vector_type(16))) char;
using float4v = __attribute__((ext_vector_type(4))) float;

__device__ __forceinline__ void gload_lds16(const void* g, void* l) {
    __builtin_amdgcn_global_load_lds(
        (const __attribute__((address_space(1))) uint32_t*)g,
        (__attribute__((address_space(3))) uint32_t*)l, 16, 0, 0);
}

__device__ __forceinline__ i32x4 mfma_i8(i32x4 a, i32x4 b, i32x4 c) {
    return __builtin_amdgcn_mfma_i32_16x16x64_i8(a, b, c, 0, 0, 0);
}

// Granule layout (R5/R9/R10-validated): granule g = (rowblk, kblk), 1024B.
// Slot l*16 <-> (row = rowblk*16 + (l&15), k bytes kblk*64 + (l>>4)*16 .. +16).
// xq:  [M/16][K/64][1024]   WqT: [N/16][K/64][1024]

// ------- pass 1a: x (f32) -> i8 q=clamp(rint(32x),±127), granule-major -------
__global__ __launch_bounds__(256) void cvt_x_kernel(const float* __restrict__ x,
                                                    char* __restrict__ xq) {
    int t = threadIdx.x;
    int g = blockIdx.x * 4 + (t >> 6);     // granule id (16384 total)
    int l = t & 63;
    int rowblk = g >> 6;                   // / KBLKS
    int kblk   = g & 63;
    int row = rowblk * 16 + (l & 15);
    int k0  = kblk * 64 + (l >> 4) * 16;
    const float4v* p = (const float4v*)(x + (size_t)row * K_DIM + k0);
    s8x16 o;
#pragma unroll
    for (int v = 0; v < 4; ++v) {
        float4v f = p[v];
#pragma unroll
        for (int j = 0; j < 4; ++j) {
            float q = __builtin_rintf(f[j] * 32.0f);
            q = fminf(127.0f, fmaxf(-127.0f, q));
            o[v * 4 + j] = (char)(int)q;
        }
    }
    *(s8x16*)(xq + (size_t)g * 1024 + l * 16) = o;
}

// --- pass 1b: W (K x N f32) -> sign -> i8, transposed + granule-major WqT ---
__global__ __launch_bounds__(256) void sign_wt_kernel(const float* __restrict__ W,
                                                      char* __restrict__ WqT) {
    __shared__ char tile_t[64][80];   // [n][k], stride 80 (16B-aligned rows)
    int j0 = blockIdx.x * 64;         // N base
    int k0 = blockIdx.y * 64;         // K base
    int tx = threadIdx.x;             // 0..63
    int ty = threadIdx.y;             // 0..3
#pragma unroll
    for (int i = 0; i < 16; ++i) {
        int kk = ty + i * 4;
        float w = W[(size_t)(k0 + kk) * N_DIM + (j0 + tx)];
        tile_t[tx][kk] = (char)((w > 0.f) - (w < 0.f));
    }
    __syncthreads();
    int t = ty * 64 + tx;
    int l = t & 63;
    int nl = (t >> 6) * 16 + (l & 15);
    int k16 = l >> 4;
    i32x4 v = *(const i32x4*)(&tile_t[nl][k16 * 16]);
    size_t g = (size_t)((j0 >> 4) + (t >> 6)) * KBLKS + (k0 >> 6);
    *(i32x4*)(WqT + g * 1024 + l * 16) = v;
}

// -------------- pass 2: 128x128-tile i8 GEMM, 2 blocks/CU --------------
// 1024 blocks, 256 threads (4 waves 2x2, per-wave 64x64, acc 64 regs).
// Both operands LDS double-buffered: 64 KB/block -> exactly 2 blocks/CU.
// Two independent barrier groups per CU drift anti-phase: one block's
// read/stage burst overlaps the other's MFMA burst (m114 mechanism).
// One barrier per tile; full-tile read burst (16 frags) for max ILP.

#define SCHED0 __builtin_amdgcn_sched_barrier(0)

// stage A panel (16 granules) + B panel (16) of tile kt into buf p.
// instr i covers granule g = i*4 + wid: rb = i*2 + (wid>>1), kk = wid&1.
#define STAGE(p, kt) do {                                                        \
    _Pragma("unroll")                                                            \
    for (int i = 0; i < 4; ++i)                                                  \
        gload_lds16(AsrcW + (size_t)i * 2 * KBLKS * 1024 + (size_t)(kt) * 2048, \
                    AdstW + (p) * 32768 + i * 4096);                             \
    _Pragma("unroll")                                                            \
    for (int i = 0; i < 4; ++i)                                                  \
        gload_lds16(BsrcW + (size_t)i * 2 * KBLKS * 1024 + (size_t)(kt) * 2048, \
                    BdstW + (p) * 32768 + i * 4096);                             \
} while (0)

#define RD_A(p, mq, kk)                                                          \
    (*(const i32x4*)(ldsc + (p) * 32768 + ((wr * 4 + (mq)) * 2 + (kk)) * 1024 + \
                     (l << 4)))
#define RD_B(p, nq, kk)                                                          \
    (*(const i32x4*)(ldsc + (p) * 32768 + 16384 +                                \
                     ((wc * 4 + (nq)) * 2 + (kk)) * 1024 + (l << 4)))

#define TILE(kt, p) do {                                                         \
    if ((kt) + 1 < NT) STAGE((p) ^ 1, (kt) + 1);                                 \
    SCHED0;                                                                      \
    _Pragma("unroll")                                                            \
    for (int kk = 0; kk < 2; ++kk) {                                             \
        _Pragma("unroll")                                                        \
        for (int mq = 0; mq < 4; ++mq) aF[mq][kk] = RD_A(p, mq, kk);             \
        _Pragma("unroll")                                                        \
        for (int nq = 0; nq < 4; ++nq) bF[nq][kk] = RD_B(p, nq, kk);             \
    }                                                                            \
    __builtin_amdgcn_s_setprio(1);                                               \
    _Pragma("unroll")                                                            \
    for (int kk = 0; kk < 2; ++kk)                                               \
        _Pragma("unroll")                                                        \
        for (int mq = 0; mq < 4; ++mq)                                           \
            _Pragma("unroll")                                                    \
            for (int nq = 0; nq < 4; ++nq)                                       \
                acc[mq][nq] = mfma_i8(aF[mq][kk], bF[nq][kk], acc[mq][nq]);      \
    __builtin_amdgcn_s_setprio(0);                                               \
    asm volatile("s_waitcnt vmcnt(0)" ::: "memory");                             \
    __syncthreads();                                                             \
    SCHED0;                                                                      \
} while (0)

__global__ __launch_bounds__(256, 2) void gemm_bin_kernel(const char* __restrict__ A,  // xq granule-major
                                                          const char* __restrict__ B,  // WqT granule-major
                                                          const float* __restrict__ bias,
                                                          float* __restrict__ C) {
    // 64 KiB: [2 buf][A 16 KB | B 16 KB]
    __shared__ __align__(16) unsigned char lds[65536];

    // T1: XCD-aware bijective swizzle (1024 wgs, 1024 % 8 == 0)
    int bid  = blockIdx.x;
    int swz  = (bid & 7) * 128 + (bid >> 3);
    int brow = (swz >> 5) << 7;    // 32 tile-rows
    int bcol = (swz & 31) << 7;    // 32 tile-cols

    int t    = threadIdx.x;
    int l    = t & 63;
    int wid  = t >> 6;     // 0..3
    int wr   = wid >> 1;   // 0..1 (M half: rows wr*64..+64)
    int wc   = wid & 1;    // 0..1 (N half: cols wc*64..+64)

    // staging sources (granule-major): instr i -> granule i*4+wid
    const char* AsrcW = A + (((size_t)(brow >> 4) + (wid >> 1)) * KBLKS
                              + (wid & 1)) * 1024 + (l << 4);
    const char* BsrcW = B + (((size_t)(bcol >> 4) + (wid >> 1)) * KBLKS
                              + (wid & 1)) * 1024 + (l << 4);
    unsigned char* AdstW = lds + wid * 1024 + (l << 4);
    unsigned char* BdstW = lds + 16384 + wid * 1024 + (l << 4);

    const char* ldsc = (const char*)lds;

    i32x4 acc[4][4];
#pragma unroll
    for (int i = 0; i < 4; ++i)
#pragma unroll
        for (int j = 0; j < 4; ++j)
            acc[i][j] = (i32x4){0, 0, 0, 0};

    i32x4 aF[4][2], bF[4][2];

    // prologue: stage tile 0 into buf 0; drain; barrier
    STAGE(0, 0);
    asm volatile("s_waitcnt vmcnt(0)" ::: "memory");
    __syncthreads();
    SCHED0;

    for (int kt2 = 0; kt2 < NT; kt2 += 2) {
        TILE(kt2, 0);
        TILE(kt2 + 1, 1);
    }

    // epilogue: C/D layout col=lane&15, row=(lane>>4)*4+reg; dequant 1/32
    int klo  = l >> 4;
    int lrow = l & 15;
    int crow = brow + wr * 64 + klo * 4;
    int ccol = bcol + wc * 64 + lrow;
#pragma unroll
    for (int nq = 0; nq < 4; ++nq) {
        int col = ccol + nq * 16;
        float bv = bias[col];
#pragma unroll
        for (int mq = 0; mq < 4; ++mq) {
            int row = crow + mq * 16;
#pragma unroll
            for (int r = 0; r < 4; ++r)
                C[(size_t)(row + r) * N_DIM + col] =
                    (float)acc[mq][nq][r] * 0.03125f + bv;
        }
    }
}

extern "C" void kernel_launch(void* const* d_in, const int* in_sizes, int n_in,
                              void* d_out, int out_size, void* d_ws, size_t ws_size,
                              hipStream_t stream) {
    const float* x = (const float*)d_in[0];   // (4096, 4096) f32
    const float* W = (const float*)d_in[1];   // (4096, 4096) f32
    const float* b = (const float*)d_in[2];   // (4096,) f32
    float* out = (float*)d_out;               // (4096, 4096) f32

    char* xq  = (char*)d_ws;                              // 16 MB: x i8, granule-major
    char* WqT = (char*)d_ws + (size_t)M_DIM * K_DIM;      // 16 MB: sign(W) i8, granule-major

    cvt_x_kernel<<<dim3((M_DIM / 16) * (K_DIM / 64) / 4), dim3(256), 0, stream>>>(x, xq);
    sign_wt_kernel<<<dim3(N_DIM / 64, K_DIM / 64), dim3(64, 4), 0, stream>>>(W, WqT);
    gemm_bin_kernel<<<dim3(1024), dim3(256), 0, stream>>>(xq, WqT, b, out);
}